// Round 1
// baseline (2289.436 us; speedup 1.0000x reference)
//
#include <hip/hip_runtime.h>
#include <cstdint>
#include <cstddef>

#define BATCH   4096
#define IN_DIM  1024
#define HID     16384
#define KSEL    32

// ---------------------------------------------------------------------------
// Kernel 1: encoder GEMM  C[B,H] = X[B,D] @ W_enc[H,D]^T + b_enc
// fp32 vector GEMM, 128x128 tile, BK=16, 256 threads, 8x8 micro-tile.
// Writes directly into d_out's sparse_encoded region.
// ---------------------------------------------------------------------------
#define BM 128
#define BN 128
#define BKK 16

__global__ __launch_bounds__(256, 2)
void enc_gemm(const float* __restrict__ X, const float* __restrict__ W,
              const float* __restrict__ bias, float* __restrict__ C)
{
    // +4 pad keeps 16B alignment (132 floats = 33*16B) and makes the
    // transposed staging stores 2-way (free) instead of 4-way.
    __shared__ float As[BKK][BM + 4];
    __shared__ float Bs[BKK][BN + 4];

    const int bn = blockIdx.x;   // HID/128 = 128
    const int bm = blockIdx.y;   // BATCH/128 = 32
    const int t  = threadIdx.x;
    const int tx = t & 15;       // 0..15  -> 8 cols each
    const int ty = t >> 4;       // 0..15  -> 8 rows each
    const int ar = t >> 2;       // staging row 0..63
    const int ac = (t & 3) << 2; // staging k-offset 0,4,8,12

    float acc[8][8];
#pragma unroll
    for (int i = 0; i < 8; ++i)
#pragma unroll
        for (int j = 0; j < 8; ++j) acc[i][j] = 0.f;

    const float* Xb = X + (size_t)(bm * BM) * IN_DIM;
    const float* Wb = W + (size_t)(bn * BN) * IN_DIM;

    for (int k0 = 0; k0 < IN_DIM; k0 += BKK) {
#pragma unroll
        for (int p = 0; p < 2; ++p) {
            const int row = ar + p * 64;
            const float4 va = *(const float4*)(Xb + (size_t)row * IN_DIM + k0 + ac);
            As[ac + 0][row] = va.x; As[ac + 1][row] = va.y;
            As[ac + 2][row] = va.z; As[ac + 3][row] = va.w;
            const float4 vb = *(const float4*)(Wb + (size_t)row * IN_DIM + k0 + ac);
            Bs[ac + 0][row] = vb.x; Bs[ac + 1][row] = vb.y;
            Bs[ac + 2][row] = vb.z; Bs[ac + 3][row] = vb.w;
        }
        __syncthreads();
#pragma unroll
        for (int kk = 0; kk < BKK; ++kk) {
            float a[8], b[8];
            *(float4*)&a[0] = *(const float4*)&As[kk][ty * 8];
            *(float4*)&a[4] = *(const float4*)&As[kk][ty * 8 + 4];
            *(float4*)&b[0] = *(const float4*)&Bs[kk][tx * 8];
            *(float4*)&b[4] = *(const float4*)&Bs[kk][tx * 8 + 4];
#pragma unroll
            for (int i = 0; i < 8; ++i)
#pragma unroll
                for (int j = 0; j < 8; ++j)
                    acc[i][j] = fmaf(a[i], b[j], acc[i][j]);
        }
        __syncthreads();
    }

    const int col0 = bn * BN + tx * 8;
    float bv[8];
#pragma unroll
    for (int j = 0; j < 8; ++j) bv[j] = bias[col0 + j];
#pragma unroll
    for (int i = 0; i < 8; ++i) {
        const size_t rowoff = (size_t)(bm * BM + ty * 8 + i) * HID + col0;
        float4 o0, o1;
        o0.x = acc[i][0] + bv[0]; o0.y = acc[i][1] + bv[1];
        o0.z = acc[i][2] + bv[2]; o0.w = acc[i][3] + bv[3];
        o1.x = acc[i][4] + bv[4]; o1.y = acc[i][5] + bv[5];
        o1.z = acc[i][6] + bv[6]; o1.w = acc[i][7] + bv[7];
        *(float4*)(C + rowoff)     = o0;
        *(float4*)(C + rowoff + 4) = o1;
    }
}

// ---------------------------------------------------------------------------
// Kernel 2: per-row top-32 by |value| via 4-level radix select on the
// abs-bit-pattern (monotonic for positive floats). Finds the EXACT key of the
// 32nd-largest, masks in place, emits compact (idx,val) lists to ws.
// One block (256 threads) per row; row stays hot in L1/L2 across passes.
// ---------------------------------------------------------------------------
__global__ __launch_bounds__(256)
void topk_rows(float* __restrict__ E, int* __restrict__ idx_out,
               float* __restrict__ val_out)
{
    const int row = blockIdx.x;
    float* p = E + (size_t)row * HID;
    const int t = threadIdx.x;

    __shared__ unsigned hist[512];
    __shared__ unsigned s_prefix;
    __shared__ int s_rank, s_eq, s_cnt;

    if (t == 0) { s_rank = KSEL; s_prefix = 0u; }

    const int shifts_arr[4] = {22, 13, 4, 0};
    const int bits_arr[4]   = {9, 9, 9, 4};

    for (int lvl = 0; lvl < 4; ++lvl) {
        const int sh = shifts_arr[lvl];
        const int nb = 1 << bits_arr[lvl];
        for (int i = t; i < nb; i += 256) hist[i] = 0u;
        __syncthreads();
        const unsigned pfx = s_prefix;
        const int psh = (lvl == 0) ? 31 : shifts_arr[lvl - 1];
        for (int i = t; i < HID; i += 256) {
            const unsigned key = __float_as_uint(p[i]) & 0x7FFFFFFFu;
            if ((key >> psh) == pfx)   // lvl 0: key>>31 == 0 always matches
                atomicAdd(&hist[(key >> sh) & (unsigned)(nb - 1)], 1u);
        }
        __syncthreads();
        if (t == 0) {
            const int r = s_rank;
            unsigned cum = 0;
            int b = nb - 1;
            for (; b > 0; --b) {
                if (cum + hist[b] >= (unsigned)r) break;
                cum += hist[b];
            }
            s_rank   = r - (int)cum;                       // equals still needed
            s_prefix = (s_prefix << bits_arr[lvl]) | (unsigned)b;
        }
        __syncthreads();
    }

    const unsigned vkey = s_prefix;   // exact abs-bit key of 32nd largest
    const int eq_need   = s_rank;     // #elements == vkey to keep (>=1)
    if (t == 0) { s_eq = 0; s_cnt = 0; }
    __syncthreads();

    // final pass: in-place mask + compact list
    for (int c = 0; c < HID / (256 * 4); ++c) {
        const int i = (c * 256 + t) * 4;
        float4 v = *(const float4*)(p + i);
        float vv[4] = {v.x, v.y, v.z, v.w};
#pragma unroll
        for (int j = 0; j < 4; ++j) {
            const unsigned key = __float_as_uint(vv[j]) & 0x7FFFFFFFu;
            bool keep = false;
            if (key > vkey) keep = true;
            else if (key == vkey) {
                const int slot = atomicAdd(&s_eq, 1);
                if (slot < eq_need) keep = true;
            }
            if (keep) {
                const int ls = atomicAdd(&s_cnt, 1);
                idx_out[row * KSEL + ls] = i + j;
                val_out[row * KSEL + ls] = vv[j];
            } else {
                vv[j] = 0.f;
            }
        }
        v.x = vv[0]; v.y = vv[1]; v.z = vv[2]; v.w = vv[3];
        *(float4*)(p + i) = v;
    }
}

// ---------------------------------------------------------------------------
// Kernel 3: transpose W_dec [1024,16384] -> WdT [16384,1024] (ws scratch)
// so the decoder's per-nnz gathers are coalesced contiguous 4KB rows.
// ---------------------------------------------------------------------------
__global__ __launch_bounds__(256)
void transpose_wdec(const float* __restrict__ Wd, float* __restrict__ WdT)
{
    __shared__ float tile[32][33];
    const int bx = blockIdx.x;           // along HID (512)
    const int by = blockIdx.y;           // along IN_DIM (32)
    const int t  = threadIdx.x;
    const int lx = t & 31, ly = t >> 5;  // 32 x 8
#pragma unroll
    for (int r = 0; r < 32; r += 8)
        tile[ly + r][lx] = Wd[(size_t)(by * 32 + ly + r) * HID + bx * 32 + lx];
    __syncthreads();
#pragma unroll
    for (int r = 0; r < 32; r += 8)
        WdT[(size_t)(bx * 32 + ly + r) * IN_DIM + by * 32 + lx] = tile[lx][ly + r];
}

// ---------------------------------------------------------------------------
// Kernel 4: sparse decode  decoded[b,:] = sum_i val_i * WdT[idx_i,:] + b_dec
// One block per row; thread t owns 4 outputs via float4 (fully coalesced).
// ---------------------------------------------------------------------------
__global__ __launch_bounds__(256)
void decode_rows(const float* __restrict__ WdT, const float* __restrict__ bd,
                 const int* __restrict__ idxs, const float* __restrict__ vals,
                 float* __restrict__ out)
{
    const int row = blockIdx.x;
    const int d   = threadIdx.x * 4;
    float4 acc = *(const float4*)(bd + d);
    for (int i = 0; i < KSEL; ++i) {
        const int   j = idxs[row * KSEL + i];
        const float v = vals[row * KSEL + i];
        const float4 w = *(const float4*)(WdT + (size_t)j * IN_DIM + d);
        acc.x = fmaf(v, w.x, acc.x);
        acc.y = fmaf(v, w.y, acc.y);
        acc.z = fmaf(v, w.z, acc.z);
        acc.w = fmaf(v, w.w, acc.w);
    }
    *(float4*)(out + (size_t)row * IN_DIM + d) = acc;
}

// Fallback decoder (no transposed copy available): strided W_dec reads.
__global__ __launch_bounds__(256)
void decode_rows_noT(const float* __restrict__ Wd, const float* __restrict__ bd,
                     const int* __restrict__ idxs, const float* __restrict__ vals,
                     float* __restrict__ out)
{
    const int row = blockIdx.x;
    const int d0  = threadIdx.x * 4;
    float acc[4];
#pragma unroll
    for (int q = 0; q < 4; ++q) acc[q] = bd[d0 + q];
    for (int i = 0; i < KSEL; ++i) {
        const int   j = idxs[row * KSEL + i];
        const float v = vals[row * KSEL + i];
#pragma unroll
        for (int q = 0; q < 4; ++q)
            acc[q] = fmaf(v, Wd[(size_t)(d0 + q) * HID + j], acc[q]);
    }
#pragma unroll
    for (int q = 0; q < 4; ++q) out[(size_t)row * IN_DIM + d0 + q] = acc[q];
}

// ---------------------------------------------------------------------------
extern "C" void kernel_launch(void* const* d_in, const int* in_sizes, int n_in,
                              void* d_out, int out_size, void* d_ws, size_t ws_size,
                              hipStream_t stream)
{
    const float* x     = (const float*)d_in[0];
    const float* W_enc = (const float*)d_in[1];
    const float* b_enc = (const float*)d_in[2];
    const float* W_dec = (const float*)d_in[3];
    const float* b_dec = (const float*)d_in[4];

    float* out     = (float*)d_out;
    float* sparse  = out;                                // [4096][16384]
    float* decoded = out + (size_t)BATCH * HID;          // [4096][1024]

    // ws layout: [idx list 512KB][val list 512KB][WdT 64MB]
    const size_t list_bytes = (size_t)BATCH * KSEL * 4;
    int*   idx_l = (int*)d_ws;
    float* val_l = (float*)((char*)d_ws + list_bytes);
    float* WdT   = (float*)((char*)d_ws + 2 * list_bytes);
    const bool have_wdt =
        ws_size >= 2 * list_bytes + (size_t)HID * IN_DIM * sizeof(float);

    // 1) encoder GEMM -> sparse region of d_out
    enc_gemm<<<dim3(HID / BN, BATCH / BM), 256, 0, stream>>>(x, W_enc, b_enc, sparse);

    // 2) per-row exact top-32 mask (in place) + compact lists
    topk_rows<<<BATCH, 256, 0, stream>>>(sparse, idx_l, val_l);

    // 3+4) decode
    if (have_wdt) {
        transpose_wdec<<<dim3(HID / 32, IN_DIM / 32), 256, 0, stream>>>(W_dec, WdT);
        decode_rows<<<BATCH, 256, 0, stream>>>(WdT, b_dec, idx_l, val_l, decoded);
    } else {
        decode_rows_noT<<<BATCH, 256, 0, stream>>>(W_dec, b_dec, idx_l, val_l, decoded);
    }
}